// Round 6
// baseline (164.805 us; speedup 1.0000x reference)
//
#include <hip/hip_runtime.h>
#include <math.h>

// Density-Aware Chamfer Loss, B=4, N=8192, fp32 3D points.
//
// Round-6: branchless packed-u32 argmin. Score = true squared distance
// d = |t|^2 + |q|^2 - 2 q.t >= 0, so bits(d) is unsigned-int monotone.
//   packed = (bits(d) & ~0x1FFF) | j       (v_and_or_b32, j = global target idx)
//   best   = min_u32(best, packed)          (v_min_u32)
// -> 6 VALU/pair (add + 3 fma + and_or + min), NO vcc chains, NO index regs.
// Truncating 13 mantissa bits perturbs candidate ranking by ~2^-10 relative;
// the final distance is recomputed exactly from idx, so only sub-0.1% ties can
// flip (negligible vs 8.4e-3 threshold). min_u32 tie-break = smallest j, which
// matches jnp.argmin's first-min rule.
//
// Per-slice partial mins go to plain-store slots keys[slice][query] (coalesced,
// no atomics, no init) when ws_size permits (~8.9 MB); otherwise fall back to
// u32 atomicMin into a 0xFF-initialized keys array (adds one memset dispatch).
//
// Dispatches (slots): partial(+zero cnt) -> reduce+count(+zero out) -> loss.

#define NPTS   8192
#define QPT    8                    // queries per thread
#define BLK    256
#define TSL    256                  // targets per slice (4KB LDS as float4)
#define NSLICE (NPTS / TSL)         // 32
#define QCH    (NPTS / (QPT * BLK)) // 4

template <bool SLOTS>
__global__ __launch_bounds__(BLK, 4) void dacl_partial(
    const float* __restrict__ gts, const float* __restrict__ preds,
    unsigned int* __restrict__ keys, int* __restrict__ cnt, int B, int N)
{
    const int bz  = blockIdx.z;      // dir*B + b
    const int dir = bz / B;
    const int b   = bz - dir * B;

    // fold cnt zeroing into this kernel (cnt first read by dacl_count, which
    // launches after us -> kernel boundary orders it)
    if (blockIdx.y == 0) {
        const int nblk = QCH * 2 * B;             // 32 blocks share the job
        const int blk  = blockIdx.x + QCH * bz;
        const int per  = (2 * B * N) / nblk;      // 2048 ints each
        int* p = cnt + blk * per;
        for (int k = threadIdx.x; k < per; k += BLK) p[k] = 0;
    }

    const float* __restrict__ q = (dir == 0 ? gts : preds) + (size_t)b * N * 3;
    const float* __restrict__ t = (dir == 0 ? preds : gts) + (size_t)b * N * 3;

    __shared__ float4 tile[TSL];
    const int tbase = blockIdx.y * TSL;

    {   // stage target slice: (tx,ty,tz,|t|^2); BLK==TSL, one point per thread
        const int j = tbase + threadIdx.x;
        const float tx = t[3 * j], ty = t[3 * j + 1], tz = t[3 * j + 2];
        tile[threadIdx.x] = make_float4(tx, ty, tz,
                                        fmaf(tx, tx, fmaf(ty, ty, tz * tz)));
    }
    __syncthreads();

    float m2x[QPT], m2y[QPT], m2z[QPT], q2[QPT];
    unsigned int best[QPT];
    const int qbase = blockIdx.x * (QPT * BLK);
    #pragma unroll
    for (int u = 0; u < QPT; ++u) {
        const int i = qbase + u * BLK + threadIdx.x;   // coalesced across lanes
        const float qx = q[3 * i], qy = q[3 * i + 1], qz = q[3 * i + 2];
        m2x[u]  = -2.0f * qx;
        m2y[u]  = -2.0f * qy;
        m2z[u]  = -2.0f * qz;
        q2[u]   = fmaf(qx, qx, fmaf(qy, qy, qz * qz));
        best[u] = 0xFFFFFFFFu;
    }

    // hot loop: 1 broadcast ds_read_b128 + QPT*(add + 3 fma + and_or + min)
    #pragma unroll 4
    for (int j = 0; j < TSL; ++j) {
        const float4 tv = tile[j];
        const unsigned int jj = (unsigned int)(tbase + j);   // 13 bits
        #pragma unroll
        for (int u = 0; u < QPT; ++u) {
            const float d = fmaf(m2x[u], tv.x,
                            fmaf(m2y[u], tv.y,
                            fmaf(m2z[u], tv.z, tv.w + q2[u])));   // true |q-t|^2 >= 0
            const unsigned int packed = (__float_as_uint(d) & 0xFFFFE000u) | jj;
            best[u] = min(best[u], packed);
        }
    }

    const size_t obase = (size_t)bz * N;
    #pragma unroll
    for (int u = 0; u < QPT; ++u) {
        const int i = qbase + u * BLK + threadIdx.x;
        if (SLOTS)
            keys[(size_t)blockIdx.y * (2 * B * N) + obase + i] = best[u];  // coalesced
        else
            atomicMin(&keys[obase + i], best[u]);
    }
}

// reduce per-slice slots -> final idx, build count histogram, zero out
__global__ __launch_bounds__(256) void dacl_count(
    const unsigned int* __restrict__ keys, int nslice, int stride,
    int* __restrict__ idxArr, int* __restrict__ cnt,
    float* __restrict__ out, int out_size, int total, int N)
{
    const int i = blockIdx.x * 256 + threadIdx.x;
    if (blockIdx.x == 0 && threadIdx.x < out_size) out[threadIdx.x] = 0.0f;
    if (i >= total) return;
    unsigned int m = 0xFFFFFFFFu;
    for (int s = 0; s < nslice; ++s)
        m = min(m, keys[(size_t)s * stride + i]);        // coalesced per slot
    const int idx = (int)(m & 0x1FFFu);
    idxArr[i] = idx;
    atomicAdd(&cnt[(i / N) * N + idx], 1);
}

__global__ __launch_bounds__(256) void dacl_loss(
    const float* __restrict__ gts, const float* __restrict__ preds,
    const int* __restrict__ idxArr, const int* __restrict__ cnt,
    float* __restrict__ out, int B, int N)
{
    const int bz  = blockIdx.y;      // dir*B + b
    const int dir = bz / B;
    const int b   = bz - dir * B;
    const float* __restrict__ q = (dir == 0 ? gts : preds) + (size_t)b * N * 3;
    const float* __restrict__ t = (dir == 0 ? preds : gts) + (size_t)b * N * 3;
    const size_t base = (size_t)bz * N;

    float s = 0.0f;
    for (int i = blockIdx.x * 256 + threadIdx.x; i < N; i += 32 * 256) {
        const int idx = idxArr[base + i];
        // recompute true NN distance exactly like the reference's gather form
        const float dx = q[3 * i]     - t[3 * idx];
        const float dy = q[3 * i + 1] - t[3 * idx + 1];
        const float dz = q[3 * i + 2] - t[3 * idx + 2];
        const float d  = dx * dx + dy * dy + dz * dz;
        const float c  = (float)cnt[base + idx];         // count^N_LAMBDA, N_LAMBDA=1
        s += 1.0f - expf(-d) / (c + 1e-6f);              // frac terms are 1 (n_x == n_gt)
    }
    for (int off = 32; off > 0; off >>= 1) s += __shfl_down(s, off, 64);
    if ((threadIdx.x & 63) == 0)
        atomicAdd(&out[b], s / (2.0f * (float)N));       // (mean1+mean2)/2
}

extern "C" void kernel_launch(void* const* d_in, const int* in_sizes, int n_in,
                              void* d_out, int out_size, void* d_ws, size_t ws_size,
                              hipStream_t stream)
{
    const float* gts   = (const float*)d_in[0];
    const float* preds = (const float*)d_in[1];

    const int N = NPTS;
    const int B = in_sizes[0] / (N * 3);                 // = 4

    const size_t nTot = (size_t)2 * B * N;               // 65536 queries total
    const size_t slotBytes = (size_t)NSLICE * nTot * sizeof(unsigned int); // 8.39MB
    const size_t tailBytes = nTot * sizeof(int) * 2;     // idxArr + cnt
    const bool slots = ws_size >= slotBytes + tailBytes;

    unsigned int* keys = (unsigned int*)d_ws;
    char* tail = (char*)d_ws + (slots ? slotBytes : nTot * sizeof(unsigned int));
    int* idxArr = (int*)tail;
    int* cnt    = (int*)(tail + nTot * sizeof(int));

    dim3 gA(QCH, NSLICE, B * 2);                         // 4 x 32 x 8 = 1024 blocks
    if (slots) {
        dacl_partial<true><<<gA, BLK, 0, stream>>>(gts, preds, keys, cnt, B, N);
        dacl_count<<<(int)(nTot / 256), 256, 0, stream>>>(
            keys, NSLICE, (int)nTot, idxArr, cnt, (float*)d_out, out_size,
            (int)nTot, N);
    } else {
        hipMemsetAsync(keys, 0xFF, nTot * sizeof(unsigned int), stream);
        dacl_partial<false><<<gA, BLK, 0, stream>>>(gts, preds, keys, cnt, B, N);
        dacl_count<<<(int)(nTot / 256), 256, 0, stream>>>(
            keys, 1, (int)nTot, idxArr, cnt, (float*)d_out, out_size,
            (int)nTot, N);
    }

    dim3 gC(32, B * 2);
    dacl_loss<<<gC, 256, 0, stream>>>(gts, preds, idxArr, cnt, (float*)d_out, B, N);
}

// Round 7
// 134.065 us; speedup vs baseline: 1.2293x; 1.2293x over previous
//
#include <hip/hip_runtime.h>
#include <math.h>

// Density-Aware Chamfer Loss, B=4, N=8192, fp32 3D points.
// NN argmin in expanded form k_j = |t_j|^2 - 2 q.t_j (same argmin as true dist).
// Target slices staged in LDS; per-slice partial argmins merged via packed u64
// atomicMin: key = (monotone_f32(k) << 32) | idx -> lowest-index tie-break,
// matching jnp.argmin. Loss recomputes the true distance from idx (exact).
//
// Round-7: IDENTICAL hot loop + epilogue to round 5 (74 us partial, the best
// measured). One change: TSL 256->128, NSLICE 32->64 => 2048 blocks = 8
// blocks/CU = 8 waves/SIMD (we had never exceeded 4). Theory: loop runs at
// 3.5 cyc/VALU-instr vs 2.0 ideal due to fma/vcc dependency stalls; doubling
// resident waves covers them. Round-6's packed-min + slot stores are reverted
// (VALUBusy x dur analysis showed they added pure stall, not fewer ops).
//
// ws layout: [keys: 2*B*N u64 (512KB)][cnt: 2*B*N int (256KB)]
// Dispatches: memset(keys=0xFF) -> partial(+zero cnt) -> count(+zero out) -> loss.

#define NPTS   8192
#define QPT    8                    // queries per thread
#define BLK    256
#define TSL    128                  // targets per slice (2KB LDS as float4)
#define NSLICE (NPTS / TSL)         // 64
#define QCH    (NPTS / (QPT * BLK)) // 4

__global__ __launch_bounds__(BLK) void dacl_partial(
    const float* __restrict__ gts, const float* __restrict__ preds,
    unsigned long long* __restrict__ keys, int* __restrict__ cnt, int B, int N)
{
    const int bz  = blockIdx.z;      // dir*B + b
    const int dir = bz / B;
    const int b   = bz - dir * B;

    // fold cnt zeroing into this kernel (cnt is first read by dacl_count,
    // which launches after us -> kernel boundary orders it)
    if (blockIdx.y == 0) {
        const int nblk  = QCH * 2 * B;            // 32 blocks share the job
        const int blk   = blockIdx.x + QCH * bz;
        const int total = 2 * B * N;              // ints
        const int per   = total / nblk;           // 2048
        int* p = cnt + blk * per;
        for (int k = threadIdx.x; k < per; k += BLK) p[k] = 0;
    }

    const float* __restrict__ q = (dir == 0 ? gts : preds) + (size_t)b * N * 3;
    const float* __restrict__ t = (dir == 0 ? preds : gts) + (size_t)b * N * 3;

    __shared__ float4 tile[TSL];
    const int tbase = blockIdx.y * TSL;

    // stage target slice: (tx,ty,tz,|t|^2) per point
    if (threadIdx.x < TSL) {
        const int j = tbase + threadIdx.x;
        const float tx = t[3 * j], ty = t[3 * j + 1], tz = t[3 * j + 2];
        tile[threadIdx.x] = make_float4(tx, ty, tz, tx * tx + ty * ty + tz * tz);
    }
    __syncthreads();

    float m2x[QPT], m2y[QPT], m2z[QPT], best[QPT];
    int   bi[QPT];
    const int qbase = blockIdx.x * (QPT * BLK);
    #pragma unroll
    for (int u = 0; u < QPT; ++u) {
        const int i = qbase + u * BLK + threadIdx.x;   // coalesced across lanes
        m2x[u]  = -2.0f * q[3 * i];
        m2y[u]  = -2.0f * q[3 * i + 1];
        m2z[u]  = -2.0f * q[3 * i + 2];
        best[u] = 3.402823466e38f;
        bi[u]   = 0;
    }

    // hot loop: 1 broadcast ds_read_b128 + QPT*(3 fma + cmp + 2 sel);
    // unroll 4 lets the compiler keep 4 ds_reads in flight
    #pragma unroll 4
    for (int j = 0; j < TSL; ++j) {
        const float4 tv = tile[j];
        #pragma unroll
        for (int u = 0; u < QPT; ++u) {
            const float k = fmaf(m2x[u], tv.x,
                            fmaf(m2y[u], tv.y,
                            fmaf(m2z[u], tv.z, tv.w)));
            if (k < best[u]) { best[u] = k; bi[u] = j; }  // strict <: first-min in-slice
        }
    }

    const size_t obase = (size_t)bz * N;
    #pragma unroll
    for (int u = 0; u < QPT; ++u) {
        const int i = qbase + u * BLK + threadIdx.x;
        unsigned int ub = __float_as_uint(best[u]);
        ub = ((int)ub < 0) ? ~ub : (ub | 0x80000000u);   // monotone f32->u32 (k can be <0)
        const unsigned long long key =
            ((unsigned long long)ub << 32) | (unsigned int)(tbase + bi[u]);
        atomicMin(&keys[obase + i], key);                // equal dist -> smallest idx wins
    }
}

__global__ __launch_bounds__(256) void dacl_count(
    const unsigned long long* __restrict__ keys, int* __restrict__ cnt,
    float* __restrict__ out, int out_size, int total, int N)
{
    const int i = blockIdx.x * 256 + threadIdx.x;
    if (blockIdx.x == 0 && threadIdx.x < out_size) out[threadIdx.x] = 0.0f;
    if (i >= total) return;
    const int idx = (int)(keys[i] & 0xFFFFFFFFull);
    const int seg = i / N;                               // dir*B + b
    atomicAdd(&cnt[seg * N + idx], 1);
}

__global__ __launch_bounds__(256) void dacl_loss(
    const float* __restrict__ gts, const float* __restrict__ preds,
    const unsigned long long* __restrict__ keys, const int* __restrict__ cnt,
    float* __restrict__ out, int B, int N)
{
    const int bz  = blockIdx.y;      // dir*B + b
    const int dir = bz / B;
    const int b   = bz - dir * B;
    const float* __restrict__ q = (dir == 0 ? gts : preds) + (size_t)b * N * 3;
    const float* __restrict__ t = (dir == 0 ? preds : gts) + (size_t)b * N * 3;
    const size_t base = (size_t)bz * N;

    float s = 0.0f;
    for (int i = blockIdx.x * 256 + threadIdx.x; i < N; i += 32 * 256) {
        const int idx = (int)(keys[base + i] & 0xFFFFFFFFull);
        // recompute true NN distance exactly like the reference's gather form
        const float dx = q[3 * i]     - t[3 * idx];
        const float dy = q[3 * i + 1] - t[3 * idx + 1];
        const float dz = q[3 * i + 2] - t[3 * idx + 2];
        const float d  = dx * dx + dy * dy + dz * dz;
        const float c  = (float)cnt[base + idx];         // count^N_LAMBDA, N_LAMBDA=1
        s += 1.0f - expf(-d) / (c + 1e-6f);              // frac terms are 1 (n_x == n_gt)
    }
    for (int off = 32; off > 0; off >>= 1) s += __shfl_down(s, off, 64);
    if ((threadIdx.x & 63) == 0)
        atomicAdd(&out[b], s / (2.0f * (float)N));       // (mean1+mean2)/2
}

extern "C" void kernel_launch(void* const* d_in, const int* in_sizes, int n_in,
                              void* d_out, int out_size, void* d_ws, size_t ws_size,
                              hipStream_t stream)
{
    const float* gts   = (const float*)d_in[0];
    const float* preds = (const float*)d_in[1];

    const int N = NPTS;
    const int B = in_sizes[0] / (N * 3);                 // = 4

    const size_t nTot = (size_t)2 * B * N;
    unsigned long long* keys = (unsigned long long*)d_ws;
    int* cnt = (int*)((char*)d_ws + nTot * sizeof(unsigned long long));

    hipMemsetAsync(keys, 0xFF, nTot * sizeof(unsigned long long), stream);

    dim3 gA(QCH, NSLICE, B * 2);                         // 4 x 64 x 8 = 2048 blocks
    dacl_partial<<<gA, BLK, 0, stream>>>(gts, preds, keys, cnt, B, N);

    dacl_count<<<(int)((nTot + 255) / 256), 256, 0, stream>>>(
        keys, cnt, (float*)d_out, out_size, (int)nTot, N);

    dim3 gC(32, B * 2);
    dacl_loss<<<gC, 256, 0, stream>>>(gts, preds, keys, cnt, (float*)d_out, B, N);
}